// Round 3
// baseline (266.868 us; speedup 1.0000x reference)
//
#include <hip/hip_runtime.h>
#include <hip/hip_bf16.h>

#define EMBED 128
#define HEADS 16
#define NEG 0.2f

typedef __attribute__((ext_vector_type(8))) short short8;
typedef __attribute__((ext_vector_type(4))) float floatx4;
typedef __attribute__((ext_vector_type(2))) float floatx2;

// async global->LDS, 16B per lane; dest must be wave-uniform base + lane*16
#define GLOAD_LDS16(g, l)                                                                  \
  __builtin_amdgcn_global_load_lds((const __attribute__((address_space(1))) unsigned int*)(g), \
                                   (__attribute__((address_space(3))) unsigned int*)(l),       \
                                   16, 0, 0)

static __device__ __forceinline__ float leaky(float x) { return x > 0.f ? x : NEG * x; }

static __device__ __forceinline__ short f2bf_bits(float f) {
  __hip_bfloat16 h = __float2bfloat16(f);
  union { __hip_bfloat16 b; short s; } u;
  u.b = h;
  return u.s;
}

// ---------------- merged prep + hist ----------------
// blocks [0,64): W1^T transpose; [64,105): folded vectors; [105,...): degree histogram

__global__ __launch_bounds__(256) void k_prep_hist(const float* __restrict__ W1,
                                                   const float* __restrict__ a_src1,
                                                   const float* __restrict__ a_dst1,
                                                   const float* __restrict__ W2,
                                                   const float* __restrict__ a_src2,
                                                   const float* __restrict__ a_dst2,
                                                   const float* __restrict__ Wc,
                                                   const float* __restrict__ b2,
                                                   const float* __restrict__ bc,
                                                   float* __restrict__ wsAll,
                                                   float* __restrict__ uvec,
                                                   float* __restrict__ cconst,
                                                   short* __restrict__ hi,
                                                   short* __restrict__ lo,
                                                   const int* __restrict__ ei, int E, int N,
                                                   int* __restrict__ deg) {
  __shared__ float tile[64][65];
  int bx = blockIdx.x;
  if (bx < 64) {
    int h = bx & 15;
    int c0 = ((bx >> 4) & 1) * 64;
    int j0 = ((bx >> 5) & 1) * 64;
    int t = threadIdx.x;
#pragma unroll
    for (int i = 0; i < 4; ++i) {
      int idx4 = i * 256 + t;
      int c = idx4 >> 4, j4 = idx4 & 15;
      float4 v = *(const float4*)&W1[(size_t)(c0 + c) * 2048 + h * 128 + j0 + j4 * 4];
      tile[c][j4 * 4 + 0] = v.x;
      tile[c][j4 * 4 + 1] = v.y;
      tile[c][j4 * 4 + 2] = v.z;
      tile[c][j4 * 4 + 3] = v.w;
    }
    __syncthreads();
#pragma unroll
    for (int i = 0; i < 4; ++i) {
      int idx = i * 256 + t;
      int j = idx >> 4, c4 = idx & 15;
      unsigned short vh[4], vl[4];
#pragma unroll
      for (int ii = 0; ii < 4; ++ii) {
        float wv = tile[c4 * 4 + ii][j];
        short hb = f2bf_bits(wv);
        float hf = __uint_as_float(((unsigned int)(unsigned short)hb) << 16);
        vh[ii] = (unsigned short)hb;
        vl[ii] = (unsigned short)f2bf_bits(wv - hf);
      }
      size_t o = (size_t)h * 16384 + (size_t)(j0 + j) * 128 + c0 + c4 * 4;
      *(ushort4*)&hi[o] = make_ushort4(vh[0], vh[1], vh[2], vh[3]);
      *(ushort4*)&lo[o] = make_ushort4(vl[0], vl[1], vl[2], vl[3]);
    }
    return;
  }
  if (bx < 105) {
    int gid = (bx - 64) * 256 + threadIdx.x;
    if (gid < 4096) {
      int sel = gid >> 11;
      int id = gid & 2047;
      int h = id >> 7, k = id & 127;
      const float* av = sel ? a_dst1 : a_src1;
      float sum = 0.f;
      const float* wrow = W1 + (size_t)k * 2048 + h * 128;
      const float* arow = av + h * 128;
#pragma unroll 4
      for (int c = 0; c < 128; ++c) sum += wrow[c] * arow[c];
      wsAll[gid] = sum;
    } else if (gid < 10240) {
      int g = gid - 4096;
      int sel = g >> 11;  // 0: Wc, 1: a_src2, 2: a_dst2
      int k = g & 2047;
      const float* v = sel == 0 ? Wc : (sel == 1 ? a_src2 : a_dst2);
      const float* wrow = W2 + (size_t)k * 128;
      float s = 0.f;
#pragma unroll 4
      for (int j = 0; j < 128; ++j) s += wrow[j] * v[j];
      uvec[g] = s;
    } else if (gid == 10240) {
      float s = 0.f;
      for (int j = 0; j < 128; ++j) s += b2[j] * Wc[j];
      *cconst = s + bc[0];
    }
    return;
  }
  // histogram (deg zeroed by prior memset)
  int i = (bx - 105) * 256 + threadIdx.x;
  int Et = E + N;
  if (i >= Et) return;
  int d = (i < E) ? ei[E + i] : (i - E);
  atomicAdd(&deg[d], 1);
}

// ---------------- merged: scan (block 0) + scatter (spin on flag) + layer-1 logits ----------------

__global__ __launch_bounds__(256) void k_scan_scat_al1(const int* __restrict__ deg,
                                                       int* __restrict__ row_ptr,
                                                       int* __restrict__ cursor,
                                                       int* __restrict__ flag,
                                                       const int* __restrict__ ei, int E, int N,
                                                       int* __restrict__ csr_src,
                                                       const float* __restrict__ x,
                                                       const float* __restrict__ wsAll,
                                                       float* __restrict__ als,
                                                       float* __restrict__ ald, int nScat) {
  __shared__ float wss[128][16], wsd[128][16];
  __shared__ int wsum[4];
  int tid = threadIdx.x;
  int bx = blockIdx.x;

  if (bx == 0) {
    // 256-thread scan, 4 elements per thread
    int lane = tid & 63, w = tid >> 6;
    int base = 0;
    for (int c0 = 0; c0 < N; c0 += 1024) {
      int i4 = c0 + tid * 4;
      int a0 = 0, a1 = 0, a2 = 0, a3 = 0;
      if (i4 + 3 < N) {
        int4 v = *(const int4*)&deg[i4];
        a0 = v.x; a1 = v.y; a2 = v.z; a3 = v.w;
      } else {
        if (i4 < N) a0 = deg[i4];
        if (i4 + 1 < N) a1 = deg[i4 + 1];
        if (i4 + 2 < N) a2 = deg[i4 + 2];
        if (i4 + 3 < N) a3 = deg[i4 + 3];
      }
      int tot = a0 + a1 + a2 + a3;
      int s = tot;
#pragma unroll
      for (int dd = 1; dd < 64; dd <<= 1) {
        int t = __shfl_up(s, dd);
        if (lane >= dd) s += t;
      }
      int wexcl = s - tot;
      if (lane == 63) wsum[w] = s;
      __syncthreads();
      int carry = 0, ctot = 0;
#pragma unroll
      for (int k = 0; k < 4; ++k) {
        int t = wsum[k];
        ctot += t;
        if (k < w) carry += t;
      }
      int p0 = base + carry + wexcl;
      int p1 = p0 + a0, p2 = p1 + a1, p3 = p2 + a2;
      if (i4 + 3 < N) {
        *(int4*)&row_ptr[i4] = make_int4(p0, p1, p2, p3);
        *(int4*)&cursor[i4] = make_int4(p0, p1, p2, p3);
      } else {
        if (i4 < N) { row_ptr[i4] = p0; cursor[i4] = p0; }
        if (i4 + 1 < N) { row_ptr[i4 + 1] = p1; cursor[i4 + 1] = p1; }
        if (i4 + 2 < N) { row_ptr[i4 + 2] = p2; cursor[i4 + 2] = p2; }
        if (i4 + 3 < N) { row_ptr[i4 + 3] = p3; cursor[i4 + 3] = p3; }
      }
      base += ctot;
      __syncthreads();
    }
    if (tid == 0) row_ptr[N] = base;
    __threadfence();
    __syncthreads();
    if (tid == 0)
      __hip_atomic_store(flag, 1, __ATOMIC_RELEASE, __HIP_MEMORY_SCOPE_AGENT);
    return;
  }

  if (bx <= nScat) {
    // scatter: wait for scan
    if (tid == 0) {
      while (!__hip_atomic_load(flag, __ATOMIC_ACQUIRE, __HIP_MEMORY_SCOPE_AGENT))
        __builtin_amdgcn_s_sleep(2);
    }
    __syncthreads();
    int i = (bx - 1) * 256 + tid;
    int Et = E + N;
    if (i >= Et) return;
    int s = (i < E) ? ei[i] : (i - E);
    int d = (i < E) ? ei[E + i] : (i - E);
    int pos = atomicAdd(&cursor[d], 1);
    csr_src[pos] = s;
    return;
  }

  // layer-1 logits
  for (int i = tid; i < 2048; i += 256) {
    int h = i >> 7, c = i & 127;
    wss[c][h] = wsAll[i];
    wsd[c][h] = wsAll[2048 + i];
  }
  __syncthreads();
  int gid = (bx - 1 - nScat) * 256 + tid;
  int n = gid >> 4, h = gid & 15;
  if (n >= N) return;
  const float4* xp = (const float4*)(x + (size_t)n * 128);
  float ps = 0.f, pd = 0.f;
#pragma unroll 8
  for (int c4 = 0; c4 < 32; ++c4) {
    float4 xv = xp[c4];
    int c = c4 * 4;
    ps += xv.x * wss[c][h] + xv.y * wss[c + 1][h] + xv.z * wss[c + 2][h] + xv.w * wss[c + 3][h];
    pd += xv.x * wsd[c][h] + xv.y * wsd[c + 1][h] + xv.z * wsd[c + 2][h] + xv.w * wsd[c + 3][h];
  }
  als[gid] = ps;
  ald[gid] = pd;
}

// ---------------- layer-1 attention: packed float2 accumulation ----------------

__global__ __launch_bounds__(256) void k_attn1h(const float* __restrict__ x,
                                                const float* __restrict__ als,
                                                const float* __restrict__ ald,
                                                const int* __restrict__ row_ptr,
                                                const int* __restrict__ csr,
                                                __hip_bfloat16* __restrict__ xaggb,
                                                int N) {
  __shared__ float accsh[2][64][37];  // 32 acc + 4 z per lane

  int tid = threadIdx.x;
  int w = tid >> 6, lane = tid & 63;
  int slot = w >> 1, half = w & 1;
  int d = blockIdx.x * 2 + slot;
  bool active = d < N;

  int e0 = 0, deg = 0;
  if (active) {
    e0 = row_ptr[d];
    deg = row_ptr[d + 1] - e0;
  }

  int g = lane >> 4, c8 = lane & 15;
  float4 aldh4 = make_float4(0.f, 0.f, 0.f, 0.f);
  if (active) aldh4 = *(const float4*)&ald[(size_t)d * 16 + g * 4];

  floatx2 acc2[4][4];
  float zacc[4] = {0.f, 0.f, 0.f, 0.f};
#pragma unroll
  for (int hh = 0; hh < 4; ++hh)
#pragma unroll
    for (int i = 0; i < 4; ++i) acc2[hh][i] = (floatx2){0.f, 0.f};

  if (active) {
    int sreg = 0;
    if (lane < deg) sreg = csr[e0 + lane];
    const float* xc = x + c8 * 8;

    int e = half;
    bool have = e < deg;
    float4 alC = make_float4(0.f, 0.f, 0.f, 0.f);
    float4 xaC = alC, xbC = alC;
    if (have) {
      int sC = (e < 64) ? __shfl(sreg, e) : csr[e0 + e];
      alC = *(const float4*)&als[(size_t)sC * 16 + g * 4];
      const float4* xp = (const float4*)(xc + (size_t)sC * 128);
      xaC = xp[0];
      xbC = xp[1];
    }
    while (have) {
      int e2 = e + 2;
      bool have2 = e2 < deg;
      float4 alN = alC, xaN = xaC, xbN = xbC;
      if (have2) {
        int sN = (e2 < 64) ? __shfl(sreg, e2) : csr[e0 + e2];
        alN = *(const float4*)&als[(size_t)sN * 16 + g * 4];
        const float4* xp2 = (const float4*)(xc + (size_t)sN * 128);
        xaN = xp2[0];
        xbN = xp2[1];
      }
      float ev0 = __expf(leaky(alC.x + aldh4.x));
      float ev1 = __expf(leaky(alC.y + aldh4.y));
      float ev2 = __expf(leaky(alC.z + aldh4.z));
      float ev3 = __expf(leaky(alC.w + aldh4.w));
      zacc[0] += ev0; zacc[1] += ev1; zacc[2] += ev2; zacc[3] += ev3;
      floatx2 x0 = {xaC.x, xaC.y}, x1 = {xaC.z, xaC.w};
      floatx2 x2 = {xbC.x, xbC.y}, x3 = {xbC.z, xbC.w};
      floatx2 e20 = {ev0, ev0}, e21 = {ev1, ev1}, e22 = {ev2, ev2}, e23 = {ev3, ev3};
      acc2[0][0] += e20 * x0; acc2[0][1] += e20 * x1; acc2[0][2] += e20 * x2; acc2[0][3] += e20 * x3;
      acc2[1][0] += e21 * x0; acc2[1][1] += e21 * x1; acc2[1][2] += e21 * x2; acc2[1][3] += e21 * x3;
      acc2[2][0] += e22 * x0; acc2[2][1] += e22 * x1; acc2[2][2] += e22 * x2; acc2[2][3] += e22 * x3;
      acc2[3][0] += e23 * x0; acc2[3][1] += e23 * x1; acc2[3][2] += e23 * x2; acc2[3][3] += e23 * x3;
      e = e2;
      have = have2;
      alC = alN;
      xaC = xaN;
      xbC = xbN;
    }
  }

  if (half == 1) {
#pragma unroll
    for (int hh = 0; hh < 4; ++hh) {
#pragma unroll
      for (int i2 = 0; i2 < 4; ++i2) {
        accsh[slot][lane][hh * 8 + i2 * 2] = acc2[hh][i2][0];
        accsh[slot][lane][hh * 8 + i2 * 2 + 1] = acc2[hh][i2][1];
      }
      accsh[slot][lane][32 + hh] = zacc[hh];
    }
  }
  __syncthreads();
  if (half == 0 && active) {
#pragma unroll
    for (int hh = 0; hh < 4; ++hh) {
      int h = g * 4 + hh;
      float z = zacc[hh] + accsh[slot][lane][32 + hh];
      float iz = 1.f / (z + 1e-16f);
      __hip_bfloat16 t[8];
#pragma unroll
      for (int i2 = 0; i2 < 4; ++i2) {
        float v0 = (acc2[hh][i2][0] + accsh[slot][lane][hh * 8 + i2 * 2]) * iz;
        float v1 = (acc2[hh][i2][1] + accsh[slot][lane][hh * 8 + i2 * 2 + 1]) * iz;
        t[i2 * 2] = __float2bfloat16(v0);
        t[i2 * 2 + 1] = __float2bfloat16(v1);
      }
      *(uint4*)(xaggb + (size_t)h * N * 128 + (size_t)d * 128 + c8 * 8) = *(uint4*)t;
    }
  }
}

// ---------------- fused: Bh+Bl staged via global_load_lds (pre-swizzled source) ----------------

__global__ __launch_bounds__(256, 2) void k_fused(const __hip_bfloat16* __restrict__ xaggb,
                                                  const short* __restrict__ w1t_hi,
                                                  const short* __restrict__ w1t_lo,
                                                  const float* __restrict__ b1,
                                                  const float* __restrict__ uvec,
                                                  float2* __restrict__ part2,
                                                  float* __restrict__ partd,
                                                  int N) {
  __shared__ float sh[512];
  __shared__ __align__(16) char Bh[32768];
  __shared__ __align__(16) char Bl[32768];
  int tid = threadIdx.x;
  int h = blockIdx.y;
  int n0 = blockIdx.x * 256;

  const char* gbh = (const char*)(w1t_hi + (size_t)h * 16384);
  const char* gbl = (const char*)(w1t_lo + (size_t)h * 16384);
#pragma unroll
  for (int i = 0; i < 8; ++i) {
    int ci = i * 256 + tid;
    int row4 = (ci >> 4) & 15;
    int srcoff = ((ci & ~15) | ((ci & 15) ^ row4)) << 4;
    GLOAD_LDS16(gbh + srcoff, Bh + ci * 16);
    GLOAD_LDS16(gbl + srcoff, Bl + ci * 16);
  }

  for (int i = tid; i < 512; i += 256) {
    int arr = i >> 7, jj = i & 127;
    sh[i] = (arr == 0) ? b1[h * 128 + jj] : uvec[(arr - 1) * 2048 + h * 128 + jj];
  }

  int w = tid >> 6, lane = tid & 63;
  int quad = lane >> 4, l15 = lane & 15;
  int nw = n0 + w * 64;

  const char* abase = (const char*)xaggb + (size_t)h * N * 256;
  short8 a[4][4];
#pragma unroll
  for (int nt = 0; nt < 4; ++nt) {
    int node = nw + nt * 16 + l15;
    if (node >= N) node = N - 1;
    const char* rowp = abase + (size_t)node * 256 + quad * 16;
#pragma unroll
    for (int ks = 0; ks < 4; ++ks)
      a[nt][ks] = *(const short8*)(rowp + ks * 64);
  }
  __syncthreads();

  floatx4 acc[4][8];
#pragma unroll
  for (int jt = 0; jt < 8; ++jt) {
    floatx4 bb = *(const floatx4*)&sh[jt * 16 + quad * 4];
#pragma unroll
    for (int nt = 0; nt < 4; ++nt) acc[nt][jt] = bb;
  }

  __builtin_amdgcn_s_setprio(1);
  for (int ks = 0; ks < 4; ++ks) {
    int xo = (((ks * 4 + quad) ^ l15) << 4);
#pragma unroll
    for (int jt = 0; jt < 8; ++jt) {
      int po = (jt * 16 + l15) * 256 + xo;
      short8 wh = *(const short8*)(Bh + po);
      short8 wl = *(const short8*)(Bl + po);
#pragma unroll
      for (int nt = 0; nt < 4; ++nt) {
        acc[nt][jt] = __builtin_amdgcn_mfma_f32_16x16x32_bf16(wh, a[nt][ks], acc[nt][jt], 0, 0, 0);
        acc[nt][jt] = __builtin_amdgcn_mfma_f32_16x16x32_bf16(wl, a[nt][ks], acc[nt][jt], 0, 0, 0);
      }
    }
  }
  __builtin_amdgcn_s_setprio(0);

  float pc[4] = {0.f, 0.f, 0.f, 0.f};
  float ps[4] = {0.f, 0.f, 0.f, 0.f};
  float pd[4] = {0.f, 0.f, 0.f, 0.f};
#pragma unroll
  for (int jt = 0; jt < 8; ++jt) {
    floatx4 uc = *(const floatx4*)&sh[128 + jt * 16 + quad * 4];
    floatx4 us = *(const floatx4*)&sh[256 + jt * 16 + quad * 4];
    floatx4 ud = *(const floatx4*)&sh[384 + jt * 16 + quad * 4];
#pragma unroll
    for (int nt = 0; nt < 4; ++nt) {
#pragma unroll
      for (int r = 0; r < 4; ++r) {
        float v = acc[nt][jt][r];
        float e = v > 0.f ? v : (__expf(v) - 1.f);
        pc[nt] += e * uc[r];
        ps[nt] += e * us[r];
        pd[nt] += e * ud[r];
      }
    }
  }
#pragma unroll
  for (int nt = 0; nt < 4; ++nt) {
    float c = pc[nt], s = ps[nt], dd = pd[nt];
    c += __shfl_xor(c, 16); c += __shfl_xor(c, 32);
    s += __shfl_xor(s, 16); s += __shfl_xor(s, 32);
    dd += __shfl_xor(dd, 16); dd += __shfl_xor(dd, 32);
    int node = nw + nt * 16 + l15;
    if (quad == 0 && node < N) {
      atomicAdd(&part2[node].x, s);
      atomicAdd(&part2[node].y, c);
      atomicAdd(&partd[node], dd);
    }
  }
}

// ---------------- layer-2 attention: 16-lane segment per dst, float2 gather ----------------

__global__ __launch_bounds__(256) void k_attn2s(const float2* __restrict__ part2,
                                                const float* __restrict__ partd,
                                                const int* __restrict__ row_ptr,
                                                const int* __restrict__ csr,
                                                const float* __restrict__ cconst,
                                                float* __restrict__ out, int N) {
  int grp = threadIdx.x >> 4, l = threadIdx.x & 15;
  int d = blockIdx.x * 16 + grp;
  if (d >= N) return;
  int e0 = row_ptr[d], deg = row_ptr[d + 1] - e0;
  float aldd = partd[d];
  float z = 0.f, num = 0.f;
  for (int e = l; e < deg; e += 16) {
    int s = csr[e0 + e];
    float2 v2 = part2[s];
    float v = __expf(leaky(v2.x + aldd));
    z += v;
    num += v * v2.y;
  }
#pragma unroll
  for (int off = 8; off; off >>= 1) {
    z += __shfl_xor(z, off);
    num += __shfl_xor(num, off);
  }
  if (l == 0) out[d] = num / (z + 1e-16f) + cconst[0];
}

// ---------------- launch ----------------

extern "C" void kernel_launch(void* const* d_in, const int* in_sizes, int n_in,
                              void* d_out, int out_size, void* d_ws, size_t ws_size,
                              hipStream_t stream) {
  const float* x      = (const float*)d_in[0];
  const int*   ei     = (const int*)d_in[1];
  const float* W1     = (const float*)d_in[2];
  const float* a_src1 = (const float*)d_in[3];
  const float* a_dst1 = (const float*)d_in[4];
  const float* b1     = (const float*)d_in[5];
  const float* W2     = (const float*)d_in[6];
  const float* a_src2 = (const float*)d_in[7];
  const float* a_dst2 = (const float*)d_in[8];
  const float* b2     = (const float*)d_in[9];
  const float* Wc     = (const float*)d_in[10];
  const float* bc     = (const float*)d_in[11];

  int N = in_sizes[0] / EMBED;
  int E = in_sizes[1] / 2;
  int Et = E + N;

  char* ws = (char*)d_ws;
  size_t off = 0;
  auto alloc = [&](size_t bytes) -> void* {
    void* p = ws + off;
    off += (bytes + 255) & ~(size_t)255;
    return p;
  };
  __hip_bfloat16* xaggb = (__hip_bfloat16*)alloc((size_t)N * 2048 * 2 + 65536);
  short* w1t_hi = (short*)alloc((size_t)262144 * 2);
  short* w1t_lo = (short*)alloc((size_t)262144 * 2);
  float* wsAll  = (float*)alloc(4096 * 4);
  float* uvec   = (float*)alloc(6144 * 4);
  float* cconst = (float*)alloc(256);
  float* als1   = (float*)alloc((size_t)N * 16 * 4);
  float* ald1   = (float*)alloc((size_t)N * 16 * 4);

  // zeroed region: [part (3N f32) | deg (N i32) | flag]
  size_t partBytes = (size_t)3 * N * 4;
  size_t degOff = (partBytes + 255) & ~(size_t)255;
  size_t flagOff = degOff + (((size_t)N * 4 + 255) & ~(size_t)255);
  size_t zeroBytes = flagOff + 256;
  char* zreg = (char*)alloc(zeroBytes);
  float* part   = (float*)zreg;
  float2* part2 = (float2*)part;
  float* partd  = part + 2 * N;
  int* deg      = (int*)(zreg + degOff);
  int* flag     = (int*)(zreg + flagOff);

  int* row_ptr  = (int*)alloc((size_t)(N + 1) * 4);
  int* cursor   = (int*)alloc((size_t)N * 4);
  int* csr      = (int*)alloc((size_t)Et * 4);

  int nScat = (Et + 255) / 256;
  int nAl1  = (N * 16 + 255) / 256;
  int nHist = (Et + 255) / 256;

  // 1: zero part/deg/flag
  hipMemsetAsync(zreg, 0, zeroBytes, stream);
  // 2: prep + histogram
  k_prep_hist<<<105 + nHist, 256, 0, stream>>>(W1, a_src1, a_dst1, W2, a_src2, a_dst2, Wc,
                                               b2, bc, wsAll, uvec, cconst, w1t_hi, w1t_lo,
                                               ei, E, N, deg);
  // 3: scan (block 0) + scatter (spin) + layer-1 logits
  k_scan_scat_al1<<<1 + nScat + nAl1, 256, 0, stream>>>(deg, row_ptr, cursor, flag, ei, E, N,
                                                        csr, x, wsAll, als1, ald1, nScat);
  // 4: layer-1 attention aggregate
  k_attn1h<<<(N + 1) / 2, 256, 0, stream>>>(x, als1, ald1, row_ptr, csr, xaggb, N);
  // 5: fused projection + elu + u-dots
  k_fused<<<dim3((N + 255) / 256, 16), 256, 0, stream>>>(xaggb, w1t_hi, w1t_lo, b1, uvec,
                                                         part2, partd, N);
  // 6: layer-2 attention
  k_attn2s<<<(N + 15) / 16, 256, 0, stream>>>(part2, partd, row_ptr, csr, cconst,
                                              (float*)d_out, N);
}

// Round 6
// 173.867 us; speedup vs baseline: 1.5349x; 1.5349x over previous
//
#include <hip/hip_runtime.h>
#include <hip/hip_bf16.h>

#define EMBED 128
#define HEADS 16
#define NEG 0.2f

typedef __attribute__((ext_vector_type(8))) short short8;
typedef __attribute__((ext_vector_type(4))) float floatx4;
typedef __attribute__((ext_vector_type(2))) float floatx2;

// async global->LDS, 16B per lane; dest must be wave-uniform base + lane*16
#define GLOAD_LDS16(g, l)                                                                  \
  __builtin_amdgcn_global_load_lds((const __attribute__((address_space(1))) unsigned int*)(g), \
                                   (__attribute__((address_space(3))) unsigned int*)(l),       \
                                   16, 0, 0)

static __device__ __forceinline__ float leaky(float x) { return x > 0.f ? x : NEG * x; }

static __device__ __forceinline__ short f2bf_bits(float f) {
  __hip_bfloat16 h = __float2bfloat16(f);
  union { __hip_bfloat16 b; short s; } u;
  u.b = h;
  return u.s;
}

// ---------------- merged prep + hist ----------------
// blocks [0,64): W1^T transpose; [64,105): folded vectors; [105,...): degree histogram

__global__ __launch_bounds__(256) void k_prep_hist(const float* __restrict__ W1,
                                                   const float* __restrict__ a_src1,
                                                   const float* __restrict__ a_dst1,
                                                   const float* __restrict__ W2,
                                                   const float* __restrict__ a_src2,
                                                   const float* __restrict__ a_dst2,
                                                   const float* __restrict__ Wc,
                                                   const float* __restrict__ b2,
                                                   const float* __restrict__ bc,
                                                   float* __restrict__ wsAll,
                                                   float* __restrict__ uvec,
                                                   float* __restrict__ cconst,
                                                   short* __restrict__ hi,
                                                   short* __restrict__ lo,
                                                   const int* __restrict__ ei, int E, int N,
                                                   int* __restrict__ deg) {
  __shared__ float tile[64][65];
  int bx = blockIdx.x;
  if (bx < 64) {
    int h = bx & 15;
    int c0 = ((bx >> 4) & 1) * 64;
    int j0 = ((bx >> 5) & 1) * 64;
    int t = threadIdx.x;
#pragma unroll
    for (int i = 0; i < 4; ++i) {
      int idx4 = i * 256 + t;
      int c = idx4 >> 4, j4 = idx4 & 15;
      float4 v = *(const float4*)&W1[(size_t)(c0 + c) * 2048 + h * 128 + j0 + j4 * 4];
      tile[c][j4 * 4 + 0] = v.x;
      tile[c][j4 * 4 + 1] = v.y;
      tile[c][j4 * 4 + 2] = v.z;
      tile[c][j4 * 4 + 3] = v.w;
    }
    __syncthreads();
#pragma unroll
    for (int i = 0; i < 4; ++i) {
      int idx = i * 256 + t;
      int j = idx >> 4, c4 = idx & 15;
      unsigned short vh[4], vl[4];
#pragma unroll
      for (int ii = 0; ii < 4; ++ii) {
        float wv = tile[c4 * 4 + ii][j];
        short hb = f2bf_bits(wv);
        float hf = __uint_as_float(((unsigned int)(unsigned short)hb) << 16);
        vh[ii] = (unsigned short)hb;
        vl[ii] = (unsigned short)f2bf_bits(wv - hf);
      }
      size_t o = (size_t)h * 16384 + (size_t)(j0 + j) * 128 + c0 + c4 * 4;
      *(ushort4*)&hi[o] = make_ushort4(vh[0], vh[1], vh[2], vh[3]);
      *(ushort4*)&lo[o] = make_ushort4(vl[0], vl[1], vl[2], vl[3]);
    }
    return;
  }
  if (bx < 105) {
    int gid = (bx - 64) * 256 + threadIdx.x;
    if (gid < 4096) {
      int sel = gid >> 11;
      int id = gid & 2047;
      int h = id >> 7, k = id & 127;
      const float* av = sel ? a_dst1 : a_src1;
      float sum = 0.f;
      const float* wrow = W1 + (size_t)k * 2048 + h * 128;
      const float* arow = av + h * 128;
#pragma unroll 4
      for (int c = 0; c < 128; ++c) sum += wrow[c] * arow[c];
      wsAll[gid] = sum;
    } else if (gid < 10240) {
      int g = gid - 4096;
      int sel = g >> 11;  // 0: Wc, 1: a_src2, 2: a_dst2
      int k = g & 2047;
      const float* v = sel == 0 ? Wc : (sel == 1 ? a_src2 : a_dst2);
      const float* wrow = W2 + (size_t)k * 128;
      float s = 0.f;
#pragma unroll 4
      for (int j = 0; j < 128; ++j) s += wrow[j] * v[j];
      uvec[g] = s;
    } else if (gid == 10240) {
      float s = 0.f;
      for (int j = 0; j < 128; ++j) s += b2[j] * Wc[j];
      *cconst = s + bc[0];
    }
    return;
  }
  // histogram (deg zeroed by prior memset)
  int i = (bx - 105) * 256 + threadIdx.x;
  int Et = E + N;
  if (i >= Et) return;
  int d = (i < E) ? ei[E + i] : (i - E);
  atomicAdd(&deg[d], 1);
}

// ---------------- merged: scan (block 0, independent) + layer-1 logits (blocks 1..) ----------------
// NO cross-block dependency: al1 depends only on x/wsAll; scan output is consumed by the
// NEXT dispatch (k_scatter), ordered by the stream. Scan latency hides under al1 work.

__global__ __launch_bounds__(256) void k_scan_al1(const int* __restrict__ deg,
                                                  int* __restrict__ row_ptr,
                                                  int* __restrict__ cursor,
                                                  const float* __restrict__ x,
                                                  const float* __restrict__ wsAll,
                                                  float* __restrict__ als,
                                                  float* __restrict__ ald, int N) {
  __shared__ float wss[128][16], wsd[128][16];
  __shared__ int wsum[4];
  int tid = threadIdx.x;
  int bx = blockIdx.x;

  if (bx == 0) {
    // 256-thread scan, 4 elements per thread (vectorized)
    int lane = tid & 63, w = tid >> 6;
    int base = 0;
    for (int c0 = 0; c0 < N; c0 += 1024) {
      int i4 = c0 + tid * 4;
      int a0 = 0, a1 = 0, a2 = 0, a3 = 0;
      if (i4 + 3 < N) {
        int4 v = *(const int4*)&deg[i4];
        a0 = v.x; a1 = v.y; a2 = v.z; a3 = v.w;
      } else {
        if (i4 < N) a0 = deg[i4];
        if (i4 + 1 < N) a1 = deg[i4 + 1];
        if (i4 + 2 < N) a2 = deg[i4 + 2];
        if (i4 + 3 < N) a3 = deg[i4 + 3];
      }
      int tot = a0 + a1 + a2 + a3;
      int s = tot;
#pragma unroll
      for (int dd = 1; dd < 64; dd <<= 1) {
        int t = __shfl_up(s, dd);
        if (lane >= dd) s += t;
      }
      int wexcl = s - tot;
      if (lane == 63) wsum[w] = s;
      __syncthreads();
      int carry = 0, ctot = 0;
#pragma unroll
      for (int k = 0; k < 4; ++k) {
        int t = wsum[k];
        ctot += t;
        if (k < w) carry += t;
      }
      int p0 = base + carry + wexcl;
      int p1 = p0 + a0, p2 = p1 + a1, p3 = p2 + a2;
      if (i4 + 3 < N) {
        *(int4*)&row_ptr[i4] = make_int4(p0, p1, p2, p3);
        *(int4*)&cursor[i4] = make_int4(p0, p1, p2, p3);
      } else {
        if (i4 < N) { row_ptr[i4] = p0; cursor[i4] = p0; }
        if (i4 + 1 < N) { row_ptr[i4 + 1] = p1; cursor[i4 + 1] = p1; }
        if (i4 + 2 < N) { row_ptr[i4 + 2] = p2; cursor[i4 + 2] = p2; }
        if (i4 + 3 < N) { row_ptr[i4 + 3] = p3; cursor[i4 + 3] = p3; }
      }
      base += ctot;
      __syncthreads();
    }
    if (tid == 0) row_ptr[N] = base;
    return;
  }

  // layer-1 logits
  for (int i = tid; i < 2048; i += 256) {
    int h = i >> 7, c = i & 127;
    wss[c][h] = wsAll[i];
    wsd[c][h] = wsAll[2048 + i];
  }
  __syncthreads();
  int gid = (bx - 1) * 256 + tid;
  int n = gid >> 4, h = gid & 15;
  if (n >= N) return;
  const float4* xp = (const float4*)(x + (size_t)n * 128);
  float ps = 0.f, pd = 0.f;
#pragma unroll 8
  for (int c4 = 0; c4 < 32; ++c4) {
    float4 xv = xp[c4];
    int c = c4 * 4;
    ps += xv.x * wss[c][h] + xv.y * wss[c + 1][h] + xv.z * wss[c + 2][h] + xv.w * wss[c + 3][h];
    pd += xv.x * wsd[c][h] + xv.y * wsd[c + 1][h] + xv.z * wsd[c + 2][h] + xv.w * wsd[c + 3][h];
  }
  als[gid] = ps;
  ald[gid] = pd;
}

// ---------------- CSR scatter (separate dispatch; sees scan output via stream order) ----------------

__global__ void k_scatter(const int* __restrict__ ei, int E, int N,
                          int* __restrict__ cursor, int* __restrict__ csr_src) {
  int i = blockIdx.x * blockDim.x + threadIdx.x;
  int Et = E + N;
  if (i >= Et) return;
  int s = (i < E) ? ei[i] : (i - E);
  int d = (i < E) ? ei[E + i] : (i - E);
  int pos = atomicAdd(&cursor[d], 1);
  csr_src[pos] = s;
}

// ---------------- layer-1 attention: packed float2 accumulation ----------------

__global__ __launch_bounds__(256) void k_attn1h(const float* __restrict__ x,
                                                const float* __restrict__ als,
                                                const float* __restrict__ ald,
                                                const int* __restrict__ row_ptr,
                                                const int* __restrict__ csr,
                                                __hip_bfloat16* __restrict__ xaggb,
                                                int N) {
  __shared__ float accsh[2][64][37];  // 32 acc + 4 z per lane

  int tid = threadIdx.x;
  int w = tid >> 6, lane = tid & 63;
  int slot = w >> 1, half = w & 1;
  int d = blockIdx.x * 2 + slot;
  bool active = d < N;

  int e0 = 0, deg = 0;
  if (active) {
    e0 = row_ptr[d];
    deg = row_ptr[d + 1] - e0;
  }

  int g = lane >> 4, c8 = lane & 15;
  float4 aldh4 = make_float4(0.f, 0.f, 0.f, 0.f);
  if (active) aldh4 = *(const float4*)&ald[(size_t)d * 16 + g * 4];

  floatx2 acc2[4][4];
  float zacc[4] = {0.f, 0.f, 0.f, 0.f};
#pragma unroll
  for (int hh = 0; hh < 4; ++hh)
#pragma unroll
    for (int i = 0; i < 4; ++i) acc2[hh][i] = (floatx2){0.f, 0.f};

  if (active) {
    int sreg = 0;
    if (lane < deg) sreg = csr[e0 + lane];
    const float* xc = x + c8 * 8;

    int e = half;
    bool have = e < deg;
    float4 alC = make_float4(0.f, 0.f, 0.f, 0.f);
    float4 xaC = alC, xbC = alC;
    if (have) {
      int sC = (e < 64) ? __shfl(sreg, e) : csr[e0 + e];
      alC = *(const float4*)&als[(size_t)sC * 16 + g * 4];
      const float4* xp = (const float4*)(xc + (size_t)sC * 128);
      xaC = xp[0];
      xbC = xp[1];
    }
    while (have) {
      int e2 = e + 2;
      bool have2 = e2 < deg;
      float4 alN = alC, xaN = xaC, xbN = xbC;
      if (have2) {
        int sN = (e2 < 64) ? __shfl(sreg, e2) : csr[e0 + e2];
        alN = *(const float4*)&als[(size_t)sN * 16 + g * 4];
        const float4* xp2 = (const float4*)(xc + (size_t)sN * 128);
        xaN = xp2[0];
        xbN = xp2[1];
      }
      float ev0 = __expf(leaky(alC.x + aldh4.x));
      float ev1 = __expf(leaky(alC.y + aldh4.y));
      float ev2 = __expf(leaky(alC.z + aldh4.z));
      float ev3 = __expf(leaky(alC.w + aldh4.w));
      zacc[0] += ev0; zacc[1] += ev1; zacc[2] += ev2; zacc[3] += ev3;
      floatx2 x0 = {xaC.x, xaC.y}, x1 = {xaC.z, xaC.w};
      floatx2 x2 = {xbC.x, xbC.y}, x3 = {xbC.z, xbC.w};
      floatx2 e20 = {ev0, ev0}, e21 = {ev1, ev1}, e22 = {ev2, ev2}, e23 = {ev3, ev3};
      acc2[0][0] += e20 * x0; acc2[0][1] += e20 * x1; acc2[0][2] += e20 * x2; acc2[0][3] += e20 * x3;
      acc2[1][0] += e21 * x0; acc2[1][1] += e21 * x1; acc2[1][2] += e21 * x2; acc2[1][3] += e21 * x3;
      acc2[2][0] += e22 * x0; acc2[2][1] += e22 * x1; acc2[2][2] += e22 * x2; acc2[2][3] += e22 * x3;
      acc2[3][0] += e23 * x0; acc2[3][1] += e23 * x1; acc2[3][2] += e23 * x2; acc2[3][3] += e23 * x3;
      e = e2;
      have = have2;
      alC = alN;
      xaC = xaN;
      xbC = xbN;
    }
  }

  if (half == 1) {
#pragma unroll
    for (int hh = 0; hh < 4; ++hh) {
#pragma unroll
      for (int i2 = 0; i2 < 4; ++i2) {
        accsh[slot][lane][hh * 8 + i2 * 2] = acc2[hh][i2][0];
        accsh[slot][lane][hh * 8 + i2 * 2 + 1] = acc2[hh][i2][1];
      }
      accsh[slot][lane][32 + hh] = zacc[hh];
    }
  }
  __syncthreads();
  if (half == 0 && active) {
#pragma unroll
    for (int hh = 0; hh < 4; ++hh) {
      int h = g * 4 + hh;
      float z = zacc[hh] + accsh[slot][lane][32 + hh];
      float iz = 1.f / (z + 1e-16f);
      __hip_bfloat16 t[8];
#pragma unroll
      for (int i2 = 0; i2 < 4; ++i2) {
        float v0 = (acc2[hh][i2][0] + accsh[slot][lane][hh * 8 + i2 * 2]) * iz;
        float v1 = (acc2[hh][i2][1] + accsh[slot][lane][hh * 8 + i2 * 2 + 1]) * iz;
        t[i2 * 2] = __float2bfloat16(v0);
        t[i2 * 2 + 1] = __float2bfloat16(v1);
      }
      *(uint4*)(xaggb + (size_t)h * N * 128 + (size_t)d * 128 + c8 * 8) = *(uint4*)t;
    }
  }
}

// ---------------- fused: Bh+Bl staged via global_load_lds (pre-swizzled source) ----------------

__global__ __launch_bounds__(256, 2) void k_fused(const __hip_bfloat16* __restrict__ xaggb,
                                                  const short* __restrict__ w1t_hi,
                                                  const short* __restrict__ w1t_lo,
                                                  const float* __restrict__ b1,
                                                  const float* __restrict__ uvec,
                                                  float2* __restrict__ part2,
                                                  float* __restrict__ partd,
                                                  int N) {
  __shared__ float sh[512];
  __shared__ __align__(16) char Bh[32768];
  __shared__ __align__(16) char Bl[32768];
  int tid = threadIdx.x;
  int h = blockIdx.y;
  int n0 = blockIdx.x * 256;

  const char* gbh = (const char*)(w1t_hi + (size_t)h * 16384);
  const char* gbl = (const char*)(w1t_lo + (size_t)h * 16384);
#pragma unroll
  for (int i = 0; i < 8; ++i) {
    int ci = i * 256 + tid;
    int row4 = (ci >> 4) & 15;
    int srcoff = ((ci & ~15) | ((ci & 15) ^ row4)) << 4;
    GLOAD_LDS16(gbh + srcoff, Bh + ci * 16);
    GLOAD_LDS16(gbl + srcoff, Bl + ci * 16);
  }

  for (int i = tid; i < 512; i += 256) {
    int arr = i >> 7, jj = i & 127;
    sh[i] = (arr == 0) ? b1[h * 128 + jj] : uvec[(arr - 1) * 2048 + h * 128 + jj];
  }

  int w = tid >> 6, lane = tid & 63;
  int quad = lane >> 4, l15 = lane & 15;
  int nw = n0 + w * 64;

  const char* abase = (const char*)xaggb + (size_t)h * N * 256;
  short8 a[4][4];
#pragma unroll
  for (int nt = 0; nt < 4; ++nt) {
    int node = nw + nt * 16 + l15;
    if (node >= N) node = N - 1;
    const char* rowp = abase + (size_t)node * 256 + quad * 16;
#pragma unroll
    for (int ks = 0; ks < 4; ++ks)
      a[nt][ks] = *(const short8*)(rowp + ks * 64);
  }
  __syncthreads();

  floatx4 acc[4][8];
#pragma unroll
  for (int jt = 0; jt < 8; ++jt) {
    floatx4 bb = *(const floatx4*)&sh[jt * 16 + quad * 4];
#pragma unroll
    for (int nt = 0; nt < 4; ++nt) acc[nt][jt] = bb;
  }

  __builtin_amdgcn_s_setprio(1);
  for (int ks = 0; ks < 4; ++ks) {
    int xo = (((ks * 4 + quad) ^ l15) << 4);
#pragma unroll
    for (int jt = 0; jt < 8; ++jt) {
      int po = (jt * 16 + l15) * 256 + xo;
      short8 wh = *(const short8*)(Bh + po);
      short8 wl = *(const short8*)(Bl + po);
#pragma unroll
      for (int nt = 0; nt < 4; ++nt) {
        acc[nt][jt] = __builtin_amdgcn_mfma_f32_16x16x32_bf16(wh, a[nt][ks], acc[nt][jt], 0, 0, 0);
        acc[nt][jt] = __builtin_amdgcn_mfma_f32_16x16x32_bf16(wl, a[nt][ks], acc[nt][jt], 0, 0, 0);
      }
    }
  }
  __builtin_amdgcn_s_setprio(0);

  float pc[4] = {0.f, 0.f, 0.f, 0.f};
  float ps[4] = {0.f, 0.f, 0.f, 0.f};
  float pd[4] = {0.f, 0.f, 0.f, 0.f};
#pragma unroll
  for (int jt = 0; jt < 8; ++jt) {
    floatx4 uc = *(const floatx4*)&sh[128 + jt * 16 + quad * 4];
    floatx4 us = *(const floatx4*)&sh[256 + jt * 16 + quad * 4];
    floatx4 ud = *(const floatx4*)&sh[384 + jt * 16 + quad * 4];
#pragma unroll
    for (int nt = 0; nt < 4; ++nt) {
#pragma unroll
      for (int r = 0; r < 4; ++r) {
        float v = acc[nt][jt][r];
        float e = v > 0.f ? v : (__expf(v) - 1.f);
        pc[nt] += e * uc[r];
        ps[nt] += e * us[r];
        pd[nt] += e * ud[r];
      }
    }
  }
#pragma unroll
  for (int nt = 0; nt < 4; ++nt) {
    float c = pc[nt], s = ps[nt], dd = pd[nt];
    c += __shfl_xor(c, 16); c += __shfl_xor(c, 32);
    s += __shfl_xor(s, 16); s += __shfl_xor(s, 32);
    dd += __shfl_xor(dd, 16); dd += __shfl_xor(dd, 32);
    int node = nw + nt * 16 + l15;
    if (quad == 0 && node < N) {
      atomicAdd(&part2[node].x, s);
      atomicAdd(&part2[node].y, c);
      atomicAdd(&partd[node], dd);
    }
  }
}

// ---------------- layer-2 attention: 16-lane segment per dst, float2 gather ----------------

__global__ __launch_bounds__(256) void k_attn2s(const float2* __restrict__ part2,
                                                const float* __restrict__ partd,
                                                const int* __restrict__ row_ptr,
                                                const int* __restrict__ csr,
                                                const float* __restrict__ cconst,
                                                float* __restrict__ out, int N) {
  int grp = threadIdx.x >> 4, l = threadIdx.x & 15;
  int d = blockIdx.x * 16 + grp;
  if (d >= N) return;
  int e0 = row_ptr[d], deg = row_ptr[d + 1] - e0;
  float aldd = partd[d];
  float z = 0.f, num = 0.f;
  for (int e = l; e < deg; e += 16) {
    int s = csr[e0 + e];
    float2 v2 = part2[s];
    float v = __expf(leaky(v2.x + aldd));
    z += v;
    num += v * v2.y;
  }
#pragma unroll
  for (int off = 8; off; off >>= 1) {
    z += __shfl_xor(z, off);
    num += __shfl_xor(num, off);
  }
  if (l == 0) out[d] = num / (z + 1e-16f) + cconst[0];
}

// ---------------- launch ----------------

extern "C" void kernel_launch(void* const* d_in, const int* in_sizes, int n_in,
                              void* d_out, int out_size, void* d_ws, size_t ws_size,
                              hipStream_t stream) {
  const float* x      = (const float*)d_in[0];
  const int*   ei     = (const int*)d_in[1];
  const float* W1     = (const float*)d_in[2];
  const float* a_src1 = (const float*)d_in[3];
  const float* a_dst1 = (const float*)d_in[4];
  const float* b1     = (const float*)d_in[5];
  const float* W2     = (const float*)d_in[6];
  const float* a_src2 = (const float*)d_in[7];
  const float* a_dst2 = (const float*)d_in[8];
  const float* b2     = (const float*)d_in[9];
  const float* Wc     = (const float*)d_in[10];
  const float* bc     = (const float*)d_in[11];

  int N = in_sizes[0] / EMBED;
  int E = in_sizes[1] / 2;
  int Et = E + N;

  char* ws = (char*)d_ws;
  size_t off = 0;
  auto alloc = [&](size_t bytes) -> void* {
    void* p = ws + off;
    off += (bytes + 255) & ~(size_t)255;
    return p;
  };
  __hip_bfloat16* xaggb = (__hip_bfloat16*)alloc((size_t)N * 2048 * 2 + 65536);
  short* w1t_hi = (short*)alloc((size_t)262144 * 2);
  short* w1t_lo = (short*)alloc((size_t)262144 * 2);
  float* wsAll  = (float*)alloc(4096 * 4);
  float* uvec   = (float*)alloc(6144 * 4);
  float* cconst = (float*)alloc(256);
  float* als1   = (float*)alloc((size_t)N * 16 * 4);
  float* ald1   = (float*)alloc((size_t)N * 16 * 4);

  // zeroed region: [part (3N f32) | deg (N i32)]
  size_t partBytes = (size_t)3 * N * 4;
  size_t degOff = (partBytes + 255) & ~(size_t)255;
  size_t zeroBytes = degOff + (((size_t)N * 4 + 255) & ~(size_t)255);
  char* zreg = (char*)alloc(zeroBytes);
  float* part   = (float*)zreg;
  float2* part2 = (float2*)part;
  float* partd  = part + 2 * N;
  int* deg      = (int*)(zreg + degOff);

  int* row_ptr  = (int*)alloc((size_t)(N + 1) * 4);
  int* cursor   = (int*)alloc((size_t)N * 4);
  int* csr      = (int*)alloc((size_t)Et * 4);

  int nAl1  = (N * 16 + 255) / 256;
  int nHist = (Et + 255) / 256;

  // 1: zero part/deg
  hipMemsetAsync(zreg, 0, zeroBytes, stream);
  // 2: prep + histogram
  k_prep_hist<<<105 + nHist, 256, 0, stream>>>(W1, a_src1, a_dst1, W2, a_src2, a_dst2, Wc,
                                               b2, bc, wsAll, uvec, cconst, w1t_hi, w1t_lo,
                                               ei, E, N, deg);
  // 3: scan (block 0, independent) + layer-1 logits
  k_scan_al1<<<1 + nAl1, 256, 0, stream>>>(deg, row_ptr, cursor, x, wsAll, als1, ald1, N);
  // 4: CSR scatter
  k_scatter<<<(Et + 255) / 256, 256, 0, stream>>>(ei, E, N, cursor, csr);
  // 5: layer-1 attention aggregate
  k_attn1h<<<(N + 1) / 2, 256, 0, stream>>>(x, als1, ald1, row_ptr, csr, xaggb, N);
  // 6: fused projection + elu + u-dots
  k_fused<<<dim3((N + 255) / 256, 16), 256, 0, stream>>>(xaggb, w1t_hi, w1t_lo, b1, uvec,
                                                         part2, partd, N);
  // 7: layer-2 attention
  k_attn2s<<<(N + 15) / 16, 256, 0, stream>>>(part2, partd, row_ptr, csr, cconst,
                                              (float*)d_out, N);
}